// Round 1
// 174.710 us; speedup vs baseline: 1.0427x; 1.0427x over previous
//
#include <hip/hip_runtime.h>
#include <hip/hip_bf16.h>
#include <cstdint>
#include <cstddef>

#define LOG2E 1.4426950408889634f

typedef __attribute__((ext_vector_type(8))) short short8;
typedef __attribute__((ext_vector_type(4))) float f32x4;

__device__ __forceinline__ float exp2f_fast(float x) { return __builtin_amdgcn_exp2f(x); }
__device__ __forceinline__ float rcp_fast(float x)   { return __builtin_amdgcn_rcpf(x); }
__device__ __forceinline__ float tanh_fast(float x) {
  float e = exp2f_fast(x * (2.0f * LOG2E));
  return 1.0f - 2.0f * rcp_fast(e + 1.0f);
}
__device__ __forceinline__ unsigned short f2b(float f) {  // f32 -> bf16 RNE
  union { float f; unsigned int u; } v; v.f = f;
  return (unsigned short)((v.u + 0x7FFFu + ((v.u >> 16) & 1u)) >> 16);
}
__device__ __forceinline__ float b2f(short h) {
  union { unsigned u; float f; } w; w.u = ((unsigned)(unsigned short)h) << 16;
  return w.f;
}

#define GLOAD_LDS16(g, l) \
  __builtin_amdgcn_global_load_lds((const __attribute__((address_space(1))) unsigned int*)(g), \
                                   (__attribute__((address_space(3))) unsigned int*)(l), 16, 0, 0)

// ---------------------------------------------------------------------------
// Skinny MFMA GEMM helper (M=32): out[b, n0..n0+127] += X @ W^T  (unchanged)
// ---------------------------------------------------------------------------
__device__ __forceinline__ void skinny_gemm(
    const float* __restrict__ W, int Kfull,
    const float* __restrict__ x0, const float* __restrict__ x1,
    const float* __restrict__ x2,
    int kbeg, int kend, int n0, float* __restrict__ out)
{
  __shared__ unsigned char sX[4096];   // 32 rows x 64 k bf16, XOR-swizzled
  const int tid = threadIdx.x, lane = tid & 63, wv = tid >> 6;
  const int l15 = lane & 15, l4 = lane >> 4;
  f32x4 acc[2][2];
#pragma unroll
  for (int m = 0; m < 2; ++m)
#pragma unroll
    for (int j = 0; j < 2; ++j) acc[m][j] = (f32x4){0.f, 0.f, 0.f, 0.f};

  const int srow = tid >> 3, skc = (tid & 7) * 8;
  const int sbyte = srow * 128 + ((skc * 2) ^ ((srow & 7) << 4));

  for (int k0 = kbeg; k0 < kend; k0 += 64) {
    const float* xs = (k0 < 1024) ? x0 : (k0 < 2048) ? x1 : x2;
    const float* xp = xs + srow * 1024 + (k0 & 1023) + skc;
    float4 a = *reinterpret_cast<const float4*>(xp);
    float4 b = *reinterpret_cast<const float4*>(xp + 4);
    short8 h;
    h[0] = (short)f2b(a.x); h[1] = (short)f2b(a.y); h[2] = (short)f2b(a.z); h[3] = (short)f2b(a.w);
    h[4] = (short)f2b(b.x); h[5] = (short)f2b(b.y); h[6] = (short)f2b(b.z); h[7] = (short)f2b(b.w);
    *reinterpret_cast<short8*>(sX + sbyte) = h;
    __syncthreads();
#pragma unroll
    for (int ks = 0; ks < 2; ++ks) {
      short8 af[2], bfr[2];
#pragma unroll
      for (int m = 0; m < 2; ++m) {
        int r = m * 16 + l15;
        af[m] = *reinterpret_cast<const short8*>(
            sX + r * 128 + (((ks * 64) + l4 * 16) ^ ((r & 7) << 4)));
      }
#pragma unroll
      for (int j = 0; j < 2; ++j) {
        int n = n0 + wv * 32 + j * 16 + l15;
        const float* wp = W + (size_t)n * Kfull + k0 + ks * 32 + l4 * 8;
        float4 wa = *reinterpret_cast<const float4*>(wp);
        float4 wb = *reinterpret_cast<const float4*>(wp + 4);
        short8 hb;
        hb[0] = (short)f2b(wa.x); hb[1] = (short)f2b(wa.y); hb[2] = (short)f2b(wa.z); hb[3] = (short)f2b(wa.w);
        hb[4] = (short)f2b(wb.x); hb[5] = (short)f2b(wb.y); hb[6] = (short)f2b(wb.z); hb[7] = (short)f2b(wb.w);
        bfr[j] = hb;
      }
#pragma unroll
      for (int m = 0; m < 2; ++m)
#pragma unroll
        for (int j = 0; j < 2; ++j)
          acc[m][j] = __builtin_amdgcn_mfma_f32_16x16x32_bf16(af[m], bfr[j], acc[m][j], 0, 0, 0);
    }
    __syncthreads();
  }
#pragma unroll
  for (int m = 0; m < 2; ++m)
#pragma unroll
    for (int j = 0; j < 2; ++j)
#pragma unroll
      for (int r = 0; r < 4; ++r)
        atomicAdd(out + (size_t)(m * 16 + l4 * 4 + r) * 1024 + (n0 + wv * 32 + j * 16 + l15),
                  acc[m][j][r]);
}

// ---------------------------------------------------------------------------
// Fused: cap + Wf -> bf16 workspace; extra blocks do att2pre (skinny MFMA).
// ---------------------------------------------------------------------------
__global__ __launch_bounds__(256) void convert_att2(
    const float* __restrict__ cap, const float* __restrict__ wf,
    unsigned short* __restrict__ capb, unsigned short* __restrict__ wfb,
    const float* __restrict__ Wd, const float* __restrict__ dh,
    float* __restrict__ att2, int nconv)
{
  if ((int)blockIdx.x < nconv) {
    const int NC = 33554432 / 8;
    const int NT = NC + 1048576 / 8;
    for (int c = blockIdx.x * 256 + threadIdx.x; c < NT; c += nconv * 256) {
      const float* s; unsigned short* d; int off;
      if (c < NC) { s = cap; d = capb; off = c * 8; }
      else        { s = wf;  d = wfb;  off = (c - NC) * 8; }
      float4 a = *reinterpret_cast<const float4*>(s + off);
      float4 b = *reinterpret_cast<const float4*>(s + off + 4);
      short8 o;
      o[0] = (short)f2b(a.x); o[1] = (short)f2b(a.y); o[2] = (short)f2b(a.z); o[3] = (short)f2b(a.w);
      o[4] = (short)f2b(b.x); o[5] = (short)f2b(b.y); o[6] = (short)f2b(b.z); o[7] = (short)f2b(b.w);
      *reinterpret_cast<short8*>(d + off) = o;
    }
  } else {
    int bid2 = blockIdx.x - nconv;
    int nt = bid2 & 7, ks = bid2 >> 3;
    skinny_gemm(Wd, 1024, dh, dh, dh, ks * 512, ks * 512 + 512, nt * 128, att2);
  }
}

// ---------------------------------------------------------------------------
// Gate GEMMs (unchanged)
// ---------------------------------------------------------------------------
__global__ __launch_bounds__(256) void gate_gemm(
    const float* __restrict__ Wg, const float* __restrict__ Ws_,
    const float* __restrict__ Wt, const float* __restrict__ word,
    const float* __restrict__ dh, const float* __restrict__ ctx,
    float* __restrict__ ztp, float* __restrict__ scp, float* __restrict__ tcp)
{
  const int nt = blockIdx.x, slot = blockIdx.y;
  if (slot < 6)
    skinny_gemm(Wg, 3072, word, dh, ctx, slot * 512, slot * 512 + 512, nt * 128, ztp);
  else if (slot < 8)
    skinny_gemm(Ws_, 1024, ctx, ctx, ctx, (slot - 6) * 512, (slot - 6) * 512 + 512, nt * 128, scp);
  else
    skinny_gemm(Wt, 2048, word, dh, dh, (slot - 8) * 512, (slot - 8) * 512 + 512, nt * 128, tcp);
}

// ---------------------------------------------------------------------------
// att_gemm3: scores[m] += sum_n tanh( cap[m,:]@Wf[n,:] + colbias[n] ) * Wa[n]
// BM=256 x BN=256, BK=64, 8 waves (2M x 4N -> wave tile 128x64), 512 threads.
// 2-slot LDS double buffer (2 x (A 32KB + B 32KB) = 128KB).
//
// De-serialized single-barrier tile body (this round's change): one s_barrier
// per K-tile; inside the body LDS reads stream CONCURRENTLY with MFMA via
// counted lgkmcnt waits:
//   STAGE(t+1)                          // 8 global_load_lds, full-tile lead
//   issue A0(8) B0(4) B1(4)             // 16 ds_read_b128
//   lgkmcnt(4)  -> MFMA(0,0)            // B1 still streaming under MFMA
//   lgkmcnt(0)  -> MFMA(0,1)
//   issue A1(8) (reuse Areg; WAR ordered by reg dep, write-back >=~80cy out)
//   lgkmcnt(0)  -> MFMA(1,0) MFMA(1,1)
//   vmcnt(0); s_barrier                 // stage(t+1) done; all waves joined
// Race-freedom: each wave's slot reads complete at its lgkmcnt(0) before the
// tile-end barrier, which precedes the next tile's stage into that slot; each
// wave's stage completes at its vmcnt(0) before the same barrier, which
// precedes the next tile's reads. At the vmcnt(0) point the stage loads are
// the ONLY outstanding VMEM ops (issued ~a full tile earlier), so no drain
// stall. sched_barrier(0) after every counted wait (rule #18).
// ---------------------------------------------------------------------------
__global__ __launch_bounds__(512, 2) void att_gemm3(
    const unsigned short* __restrict__ capb, const unsigned short* __restrict__ wfb,
    const float* __restrict__ att2pre, const float* __restrict__ bfv,
    const float* __restrict__ bdv, const float* __restrict__ Wa,
    float* __restrict__ scores)
{
  __shared__ __align__(16) unsigned char lds[131072];   // 2 slots x 65536
  const int tid = threadIdx.x, lane = tid & 63, wv = tid >> 6;
  // bijective XCD chunking: nwg=512, 8 XCDs, 64 jobs/XCD
  const int j = ((int)blockIdx.x & 7) * 64 + ((int)blockIdx.x >> 3);
  const int mt = j >> 2, nt = j & 3;            // 128 m-tiles x 4 n-tiles
  const int m0 = mt << 8, n0 = nt << 8;
  const int bb = m0 >> 10;                      // batch (256 | 1024)
  const int wm = wv >> 2, wn = wv & 3;          // 2M x 4N
  const int l15 = lane & 15, l4 = lane >> 4;
  const int r8 = lane >> 3, c8 = lane & 7;
  const unsigned swb = (unsigned)((l15 & 7) << 4);

  // per-lane global stage sources (row = 2048 B); inverse-swizzled column
  const unsigned char* aSrc = (const unsigned char*)capb +
      (size_t)(m0 + wv * 32 + r8) * 2048 + ((c8 * 16) ^ (r8 << 4));
  const unsigned char* bSrc = (const unsigned char*)wfb +
      (size_t)(n0 + wv * 32 + r8) * 2048 + ((c8 * 16) ^ (r8 << 4));
  const unsigned ldsBase = (unsigned)(size_t)(&lds[0]);

  f32x4 acc[8][4];
#pragma unroll
  for (int mf = 0; mf < 8; ++mf)
#pragma unroll
    for (int nf = 0; nf < 4; ++nf) acc[mf][nf] = (f32x4){0.f, 0.f, 0.f, 0.f};

#define STAGE(t) do { \
    const int sl__ = (t) & 1; \
    unsigned char* da__ = lds + sl__ * 65536 + wv * 4096; \
    unsigned char* db__ = lds + sl__ * 65536 + 32768 + wv * 4096; \
    const unsigned char* ga__ = aSrc + (t) * 128; \
    const unsigned char* gb__ = bSrc + (t) * 128; \
    GLOAD_LDS16(ga__,          da__); \
    GLOAD_LDS16(ga__ + 16384,  da__ + 1024); \
    GLOAD_LDS16(ga__ + 32768,  da__ + 2048); \
    GLOAD_LDS16(ga__ + 49152,  da__ + 3072); \
    GLOAD_LDS16(gb__,          db__); \
    GLOAD_LDS16(gb__ + 16384,  db__ + 1024); \
    GLOAD_LDS16(gb__ + 32768,  db__ + 2048); \
    GLOAD_LDS16(gb__ + 49152,  db__ + 3072); \
  } while (0)

#define DSREAD(dst, addr) \
  asm volatile("ds_read_b128 %0, %1" : "=v"(dst) : "v"(addr))

#define READ_A(rh) do { \
_Pragma("unroll") \
    for (int mf = 0; mf < 4; ++mf) \
_Pragma("unroll") \
      for (int ks = 0; ks < 2; ++ks) { \
        unsigned r__ = (unsigned)(wm * 128 + (rh) * 64 + mf * 16 + l15); \
        DSREAD(Areg[mf * 2 + ks], sA + r__ * 128 + (((unsigned)(ks * 64 + l4 * 16)) ^ swb)); \
      } \
  } while (0)

#define READ_B(Breg, ch) do { \
_Pragma("unroll") \
    for (int nf = 0; nf < 2; ++nf) \
_Pragma("unroll") \
      for (int ks = 0; ks < 2; ++ks) { \
        unsigned c__ = (unsigned)(wn * 64 + (ch) * 32 + nf * 16 + l15); \
        DSREAD(Breg[nf * 2 + ks], sB + c__ * 128 + (((unsigned)(ks * 64 + l4 * 16)) ^ swb)); \
      } \
  } while (0)

#define MFMA16(rh, ch, Breg) do { \
_Pragma("unroll") \
    for (int mf = 0; mf < 4; ++mf) \
_Pragma("unroll") \
      for (int nf = 0; nf < 2; ++nf) \
_Pragma("unroll") \
        for (int ks = 0; ks < 2; ++ks) \
          acc[(rh) * 4 + mf][(ch) * 2 + nf] = __builtin_amdgcn_mfma_f32_16x16x32_bf16( \
              Areg[mf * 2 + ks], Breg[nf * 2 + ks], acc[(rh) * 4 + mf][(ch) * 2 + nf], 0, 0, 0); \
  } while (0)

#define WAIT_LGKM(n) do { \
    asm volatile("s_waitcnt lgkmcnt(" #n ")" ::: "memory"); \
    __builtin_amdgcn_sched_barrier(0); \
  } while (0)

  short8 Areg[8], B0reg[4], B1reg[4];

  // prologue: stage tile 0, drain, join
  STAGE(0);
  asm volatile("s_waitcnt vmcnt(0)" ::: "memory");
  asm volatile("s_barrier" ::: "memory");

  for (int t = 0; t < 16; ++t) {
    const unsigned sA = ldsBase + (unsigned)((t & 1) * 65536);
    const unsigned sB = sA + 32768u;

    // stage t+1 into the other slot (its previous readers finished before
    // the barrier we just passed)
    if (t < 15) STAGE(t + 1);

    // 16-deep read burst: A-half0, B-colhalf0, B-colhalf1
    READ_A(0);
    READ_B(B0reg, 0);
    READ_B(B1reg, 1);

    WAIT_LGKM(4);                       // A0 + B0 landed; B1 still in flight
    __builtin_amdgcn_s_setprio(1);
    MFMA16(0, 0, B0reg);
    __builtin_amdgcn_s_setprio(0);

    WAIT_LGKM(0);                       // B1 landed
    __builtin_amdgcn_s_setprio(1);
    MFMA16(0, 1, B1reg);
    __builtin_amdgcn_s_setprio(0);

    READ_A(1);                          // reuse Areg; streams under (0,1)
    WAIT_LGKM(0);                       // A1 landed
    __builtin_amdgcn_s_setprio(1);
    MFMA16(1, 0, B0reg);
    MFMA16(1, 1, B1reg);
    __builtin_amdgcn_s_setprio(0);

    if (t < 15) {
      asm volatile("s_waitcnt vmcnt(0)" ::: "memory");  // only stage(t+1) outstanding
      asm volatile("s_barrier" ::: "memory");
    }
  }

  // epilogue: s[m] = sum_n tanh(acc + colb[n]) * Wa[n], reduce over l15
  float colb[4], wav[4];
#pragma unroll
  for (int nf = 0; nf < 4; ++nf) {
    int cg = n0 + wn * 64 + nf * 16 + l15;
    colb[nf] = att2pre[bb * 1024 + cg] + bfv[cg] + bdv[cg];
    wav[nf]  = Wa[cg];
  }
#pragma unroll
  for (int mf = 0; mf < 8; ++mf) {
#pragma unroll
    for (int r = 0; r < 4; ++r) {
      float s = tanh_fast(acc[mf][0][r] + colb[0]) * wav[0]
              + tanh_fast(acc[mf][1][r] + colb[1]) * wav[1]
              + tanh_fast(acc[mf][2][r] + colb[2]) * wav[2]
              + tanh_fast(acc[mf][3][r] + colb[3]) * wav[3];
      s += __shfl_xor(s, 1);
      s += __shfl_xor(s, 2);
      s += __shfl_xor(s, 4);
      s += __shfl_xor(s, 8);
      if (l15 == 0)
        atomicAdd(scores + (m0 + wm * 128 + mf * 16 + l4 * 4 + r), s);
    }
  }
#undef STAGE
#undef DSREAD
#undef READ_A
#undef READ_B
#undef MFMA16
#undef WAIT_LGKM
}

// ---------------------------------------------------------------------------
__global__ __launch_bounds__(256) void softmax_k(
    const float* __restrict__ scores, const int* __restrict__ mask,
    float* __restrict__ alpha)
{
  const int b = blockIdx.x, tid = threadIdx.x;
  __shared__ float red[8];
  float s[4];
  float mx = -3.0e38f;
#pragma unroll
  for (int i = 0; i < 4; ++i) {
    int l = tid + i * 256;
    float v = scores[b * 1024 + l];
    v = (mask[b * 1024 + l] == 0) ? -1.0e10f : v;
    s[i] = v;
    mx = fmaxf(mx, v);
  }
  for (int off = 1; off < 64; off <<= 1) mx = fmaxf(mx, __shfl_xor(mx, off));
  int wv = tid >> 6;
  if ((tid & 63) == 0) red[wv] = mx;
  __syncthreads();
  mx = fmaxf(fmaxf(red[0], red[1]), fmaxf(red[2], red[3]));
  float sum = 0.f;
#pragma unroll
  for (int i = 0; i < 4; ++i) {
    s[i] = exp2f_fast((s[i] - mx) * LOG2E);
    sum += s[i];
  }
  for (int off = 1; off < 64; off <<= 1) sum += __shfl_xor(sum, off);
  if ((tid & 63) == 0) red[4 + wv] = sum;
  __syncthreads();
  sum = red[4] + red[5] + red[6] + red[7];
  float inv = 1.0f / sum;
#pragma unroll
  for (int i = 0; i < 4; ++i) alpha[b * 1024 + tid + i * 256] = s[i] * inv;
}

// ---------------------------------------------------------------------------
__global__ __launch_bounds__(256) void ctx_kb(
    const unsigned short* __restrict__ capb, const float* __restrict__ alpha,
    float* __restrict__ ctx)
{
  const int b = blockIdx.y, lc = blockIdx.x;
  const int dc = threadIdx.x & 127, loff = threadIdx.x >> 7;
  float acc[8] = {0.f, 0.f, 0.f, 0.f, 0.f, 0.f, 0.f, 0.f};
  for (int l = lc * 128 + loff; l < lc * 128 + 128; l += 2) {
    float av = alpha[b * 1024 + l];
    if (av != 0.f) {
      short8 v = *reinterpret_cast<const short8*>(capb + (((size_t)(b * 1024 + l)) << 10) + dc * 8);
#pragma unroll
      for (int j = 0; j < 8; ++j) acc[j] += av * b2f(v[j]);
    }
  }
#pragma unroll
  for (int j = 0; j < 8; ++j) atomicAdd(ctx + b * 1024 + dc * 8 + j, acc[j]);
}

// ---------------------------------------------------------------------------
__global__ __launch_bounds__(256) void final_k(
    const float* __restrict__ ztp, const float* __restrict__ scp,
    const float* __restrict__ tcp, const float* __restrict__ bg,
    const float* __restrict__ bs, const float* __restrict__ bt,
    float* __restrict__ out)
{
  const int idx = blockIdx.x * 256 + threadIdx.x;
  const int d = idx & 1023;
  float z  = rcp_fast(1.0f + exp2f_fast(-(ztp[idx] + bg[d]) * LOG2E));
  float sc = tanh_fast(scp[idx] + bs[d]);
  float tc = tanh_fast(tcp[idx] + bt[d]);
  out[idx] = z * sc + (1.0f - z) * tc;
}

extern "C" void kernel_launch(void* const* d_in, const int* in_sizes, int n_in,
                              void* d_out, int out_size, void* d_ws, size_t ws_size,
                              hipStream_t stream) {
  const float* cap  = (const float*)d_in[0];
  const float* dh   = (const float*)d_in[1];
  const float* word = (const float*)d_in[2];
  const int*   mask = (const int*)d_in[3];
  const float* Wf   = (const float*)d_in[4];
  const float* bf   = (const float*)d_in[5];
  const float* Wd   = (const float*)d_in[6];
  const float* bd   = (const float*)d_in[7];
  const float* Wa   = (const float*)d_in[8];
  // d_in[9] = ba: softmax-invariant, dropped.
  const float* Wg   = (const float*)d_in[10];
  const float* bg   = (const float*)d_in[11];
  const float* Ws   = (const float*)d_in[12];
  const float* bs   = (const float*)d_in[13];
  const float* Wt   = (const float*)d_in[14];
  const float* bt   = (const float*)d_in[15];

  float* out_g = (float*)d_out;            // (32,1024) gated_context
  float* alpha = (float*)d_out + 32768;    // (32,1024) alpha

  float* att2pre = (float*)d_ws;           // 6 x 32768 f32
  float* scores  = att2pre + 32768;
  float* ctx     = scores + 32768;
  float* ztp     = ctx + 32768;
  float* scp     = ztp + 32768;
  float* tcp     = scp + 32768;
  unsigned short* capb = (unsigned short*)((char*)d_ws + 786432);
  unsigned short* wfb  = capb + 33554432;

  hipMemsetAsync(d_ws, 0, 6 * 32768 * sizeof(float), stream);

  convert_att2<<<2064, 256, 0, stream>>>(cap, Wf, capb, wfb, Wd, dh, att2pre, 2048);
  att_gemm3<<<512, 512, 0, stream>>>(capb, wfb, att2pre, bf, bd, Wa, scores);
  softmax_k<<<32, 256, 0, stream>>>(scores, mask, alpha);
  ctx_kb<<<dim3(8, 32), 256, 0, stream>>>(capb, alpha, ctx);
  gate_gemm<<<dim3(8, 12), 256, 0, stream>>>(Wg, Ws, Wt, word, dh, ctx, ztp, scp, tcp);
  final_k<<<128, 256, 0, stream>>>(ztp, scp, tcp, bg, bs, bt, out_g);
}

// Round 2
// 170.928 us; speedup vs baseline: 1.0658x; 1.0221x over previous
//
#include <hip/hip_runtime.h>
#include <hip/hip_bf16.h>
#include <cstdint>
#include <cstddef>

#define LOG2E 1.4426950408889634f

typedef __attribute__((ext_vector_type(8))) short short8;
typedef __attribute__((ext_vector_type(4))) float f32x4;

__device__ __forceinline__ float exp2f_fast(float x) { return __builtin_amdgcn_exp2f(x); }
__device__ __forceinline__ float rcp_fast(float x)   { return __builtin_amdgcn_rcpf(x); }
__device__ __forceinline__ float tanh_fast(float x) {
  float e = exp2f_fast(x * (2.0f * LOG2E));
  return 1.0f - 2.0f * rcp_fast(e + 1.0f);
}
__device__ __forceinline__ unsigned short f2b(float f) {  // f32 -> bf16 RNE
  union { float f; unsigned int u; } v; v.f = f;
  return (unsigned short)((v.u + 0x7FFFu + ((v.u >> 16) & 1u)) >> 16);
}
__device__ __forceinline__ float b2f(short h) {
  union { unsigned u; float f; } w; w.u = ((unsigned)(unsigned short)h) << 16;
  return w.f;
}

#define GLOAD_LDS16(g, l) \
  __builtin_amdgcn_global_load_lds((const __attribute__((address_space(1))) unsigned int*)(g), \
                                   (__attribute__((address_space(3))) unsigned int*)(l), 16, 0, 0)

// ---------------------------------------------------------------------------
// Skinny MFMA GEMM helper (M=32): out[b, n0..n0+127] += X @ W^T  (unchanged)
// ---------------------------------------------------------------------------
__device__ __forceinline__ void skinny_gemm(
    const float* __restrict__ W, int Kfull,
    const float* __restrict__ x0, const float* __restrict__ x1,
    const float* __restrict__ x2,
    int kbeg, int kend, int n0, float* __restrict__ out)
{
  __shared__ unsigned char sX[4096];   // 32 rows x 64 k bf16, XOR-swizzled
  const int tid = threadIdx.x, lane = tid & 63, wv = tid >> 6;
  const int l15 = lane & 15, l4 = lane >> 4;
  f32x4 acc[2][2];
#pragma unroll
  for (int m = 0; m < 2; ++m)
#pragma unroll
    for (int j = 0; j < 2; ++j) acc[m][j] = (f32x4){0.f, 0.f, 0.f, 0.f};

  const int srow = tid >> 3, skc = (tid & 7) * 8;
  const int sbyte = srow * 128 + ((skc * 2) ^ ((srow & 7) << 4));

  for (int k0 = kbeg; k0 < kend; k0 += 64) {
    const float* xs = (k0 < 1024) ? x0 : (k0 < 2048) ? x1 : x2;
    const float* xp = xs + srow * 1024 + (k0 & 1023) + skc;
    float4 a = *reinterpret_cast<const float4*>(xp);
    float4 b = *reinterpret_cast<const float4*>(xp + 4);
    short8 h;
    h[0] = (short)f2b(a.x); h[1] = (short)f2b(a.y); h[2] = (short)f2b(a.z); h[3] = (short)f2b(a.w);
    h[4] = (short)f2b(b.x); h[5] = (short)f2b(b.y); h[6] = (short)f2b(b.z); h[7] = (short)f2b(b.w);
    *reinterpret_cast<short8*>(sX + sbyte) = h;
    __syncthreads();
#pragma unroll
    for (int ks = 0; ks < 2; ++ks) {
      short8 af[2], bfr[2];
#pragma unroll
      for (int m = 0; m < 2; ++m) {
        int r = m * 16 + l15;
        af[m] = *reinterpret_cast<const short8*>(
            sX + r * 128 + (((ks * 64) + l4 * 16) ^ ((r & 7) << 4)));
      }
#pragma unroll
      for (int j = 0; j < 2; ++j) {
        int n = n0 + wv * 32 + j * 16 + l15;
        const float* wp = W + (size_t)n * Kfull + k0 + ks * 32 + l4 * 8;
        float4 wa = *reinterpret_cast<const float4*>(wp);
        float4 wb = *reinterpret_cast<const float4*>(wp + 4);
        short8 hb;
        hb[0] = (short)f2b(wa.x); hb[1] = (short)f2b(wa.y); hb[2] = (short)f2b(wa.z); hb[3] = (short)f2b(wa.w);
        hb[4] = (short)f2b(wb.x); hb[5] = (short)f2b(wb.y); hb[6] = (short)f2b(wb.z); hb[7] = (short)f2b(wb.w);
        bfr[j] = hb;
      }
#pragma unroll
      for (int m = 0; m < 2; ++m)
#pragma unroll
        for (int j = 0; j < 2; ++j)
          acc[m][j] = __builtin_amdgcn_mfma_f32_16x16x32_bf16(af[m], bfr[j], acc[m][j], 0, 0, 0);
    }
    __syncthreads();
  }
#pragma unroll
  for (int m = 0; m < 2; ++m)
#pragma unroll
    for (int j = 0; j < 2; ++j)
#pragma unroll
      for (int r = 0; r < 4; ++r)
        atomicAdd(out + (size_t)(m * 16 + l4 * 4 + r) * 1024 + (n0 + wv * 32 + j * 16 + l15),
                  acc[m][j][r]);
}

// ---------------------------------------------------------------------------
// Fused: cap + Wf -> bf16 workspace; extra blocks do att2pre (skinny MFMA).
// ---------------------------------------------------------------------------
__global__ __launch_bounds__(256) void convert_att2(
    const float* __restrict__ cap, const float* __restrict__ wf,
    unsigned short* __restrict__ capb, unsigned short* __restrict__ wfb,
    const float* __restrict__ Wd, const float* __restrict__ dh,
    float* __restrict__ att2, int nconv)
{
  if ((int)blockIdx.x < nconv) {
    const int NC = 33554432 / 8;
    const int NT = NC + 1048576 / 8;
    for (int c = blockIdx.x * 256 + threadIdx.x; c < NT; c += nconv * 256) {
      const float* s; unsigned short* d; int off;
      if (c < NC) { s = cap; d = capb; off = c * 8; }
      else        { s = wf;  d = wfb;  off = (c - NC) * 8; }
      float4 a = *reinterpret_cast<const float4*>(s + off);
      float4 b = *reinterpret_cast<const float4*>(s + off + 4);
      short8 o;
      o[0] = (short)f2b(a.x); o[1] = (short)f2b(a.y); o[2] = (short)f2b(a.z); o[3] = (short)f2b(a.w);
      o[4] = (short)f2b(b.x); o[5] = (short)f2b(b.y); o[6] = (short)f2b(b.z); o[7] = (short)f2b(b.w);
      *reinterpret_cast<short8*>(d + off) = o;
    }
  } else {
    int bid2 = blockIdx.x - nconv;
    int nt = bid2 & 7, ks = bid2 >> 3;
    skinny_gemm(Wd, 1024, dh, dh, dh, ks * 512, ks * 512 + 512, nt * 128, att2);
  }
}

// ---------------------------------------------------------------------------
// Gate GEMMs (unchanged)
// ---------------------------------------------------------------------------
__global__ __launch_bounds__(256) void gate_gemm(
    const float* __restrict__ Wg, const float* __restrict__ Ws_,
    const float* __restrict__ Wt, const float* __restrict__ word,
    const float* __restrict__ dh, const float* __restrict__ ctx,
    float* __restrict__ ztp, float* __restrict__ scp, float* __restrict__ tcp)
{
  const int nt = blockIdx.x, slot = blockIdx.y;
  if (slot < 6)
    skinny_gemm(Wg, 3072, word, dh, ctx, slot * 512, slot * 512 + 512, nt * 128, ztp);
  else if (slot < 8)
    skinny_gemm(Ws_, 1024, ctx, ctx, ctx, (slot - 6) * 512, (slot - 6) * 512 + 512, nt * 128, scp);
  else
    skinny_gemm(Wt, 2048, word, dh, dh, (slot - 8) * 512, (slot - 8) * 512 + 512, nt * 128, tcp);
}

// ---------------------------------------------------------------------------
// att_gemm3: scores[m] += sum_n tanh( cap[m,:]@Wf[n,:] + colbias[n] ) * Wa[n]
// BM=256 x BN=256, BK=64, 8 waves (2M x 4N -> wave tile 128x64), 512 threads.
// 2-slot LDS double buffer. One s_barrier per K-tile.
//
// Round-2 change: quarter-pipelined A reads (4 quarters x 32 rows, ping-pong
// Aq0/Aq1 register buffers) so every lgkm wait is COUNTED against a prefetch
// issued ~2 MFMA-clusters earlier. Per tile:
//   burst: AQ0, B(ch0), B(ch1), AQ1           (16 ds_read)
//   lgkm(8)  -> MFMA q0xc0                    (AQ1,Bch1 streaming)
//   lgkm(4)  -> MFMA q0xc1
//   lgkm(0)  -> issue AQ2 -> MFMA q1xc0,q1xc1 (AQ2 streaming)
//   issue AQ3 -> lgkm(4) -> MFMA q2xc0,q2xc1  (AQ3 streaming)
//   lgkm(0)  -> MFMA q3xc0,q3xc1
//   vmcnt(0); s_barrier                       (stage(t+1) issued at tile top)
// Register budget unchanged vs round 1 (no extra buffers: stay under the
// 256-reg/wave cliff; acc 128 AGPR + ~112 VGPR).
// ---------------------------------------------------------------------------
__global__ __launch_bounds__(512, 2) void att_gemm3(
    const unsigned short* __restrict__ capb, const unsigned short* __restrict__ wfb,
    const float* __restrict__ att2pre, const float* __restrict__ bfv,
    const float* __restrict__ bdv, const float* __restrict__ Wa,
    float* __restrict__ scores)
{
  __shared__ __align__(16) unsigned char lds[131072];   // 2 slots x 65536
  const int tid = threadIdx.x, lane = tid & 63, wv = tid >> 6;
  // bijective XCD chunking: nwg=512, 8 XCDs, 64 jobs/XCD
  const int j = ((int)blockIdx.x & 7) * 64 + ((int)blockIdx.x >> 3);
  const int mt = j >> 2, nt = j & 3;            // 128 m-tiles x 4 n-tiles
  const int m0 = mt << 8, n0 = nt << 8;
  const int bb = m0 >> 10;                      // batch (256 | 1024)
  const int wm = wv >> 2, wn = wv & 3;          // 2M x 4N
  const int l15 = lane & 15, l4 = lane >> 4;
  const int r8 = lane >> 3, c8 = lane & 7;
  const unsigned swb = (unsigned)((l15 & 7) << 4);

  // per-lane global stage sources (row = 2048 B); inverse-swizzled column
  const unsigned char* aSrc = (const unsigned char*)capb +
      (size_t)(m0 + wv * 32 + r8) * 2048 + ((c8 * 16) ^ (r8 << 4));
  const unsigned char* bSrc = (const unsigned char*)wfb +
      (size_t)(n0 + wv * 32 + r8) * 2048 + ((c8 * 16) ^ (r8 << 4));
  const unsigned ldsBase = (unsigned)(size_t)(&lds[0]);

  f32x4 acc[8][4];
#pragma unroll
  for (int mf = 0; mf < 8; ++mf)
#pragma unroll
    for (int nf = 0; nf < 4; ++nf) acc[mf][nf] = (f32x4){0.f, 0.f, 0.f, 0.f};

#define STAGE(t) do { \
    const int sl__ = (t) & 1; \
    unsigned char* da__ = lds + sl__ * 65536 + wv * 4096; \
    unsigned char* db__ = lds + sl__ * 65536 + 32768 + wv * 4096; \
    const unsigned char* ga__ = aSrc + (t) * 128; \
    const unsigned char* gb__ = bSrc + (t) * 128; \
    GLOAD_LDS16(ga__,          da__); \
    GLOAD_LDS16(ga__ + 16384,  da__ + 1024); \
    GLOAD_LDS16(ga__ + 32768,  da__ + 2048); \
    GLOAD_LDS16(ga__ + 49152,  da__ + 3072); \
    GLOAD_LDS16(gb__,          db__); \
    GLOAD_LDS16(gb__ + 16384,  db__ + 1024); \
    GLOAD_LDS16(gb__ + 32768,  db__ + 2048); \
    GLOAD_LDS16(gb__ + 49152,  db__ + 3072); \
  } while (0)

#define DSREAD(dst, addr) \
  asm volatile("ds_read_b128 %0, %1" : "=v"(dst) : "v"(addr))

// read one A quarter (32 rows): 4 x ds_read_b128 into dst[0..3]
#define READ_AQ(dst, q) do { \
_Pragma("unroll") \
    for (int mf2 = 0; mf2 < 2; ++mf2) \
_Pragma("unroll") \
      for (int ks = 0; ks < 2; ++ks) { \
        unsigned r__ = (unsigned)(wm * 128 + (q) * 32 + mf2 * 16 + l15); \
        DSREAD(dst[mf2 * 2 + ks], sA + r__ * 128 + (((unsigned)(ks * 64 + l4 * 16)) ^ swb)); \
      } \
  } while (0)

// read one B column-half (32 cols): 4 x ds_read_b128 into Breg[ch*4 ..]
#define READ_B(ch) do { \
_Pragma("unroll") \
    for (int nf = 0; nf < 2; ++nf) \
_Pragma("unroll") \
      for (int ks = 0; ks < 2; ++ks) { \
        unsigned c__ = (unsigned)(wn * 64 + (ch) * 32 + nf * 16 + l15); \
        DSREAD(Breg[(ch) * 4 + nf * 2 + ks], sB + c__ * 128 + (((unsigned)(ks * 64 + l4 * 16)) ^ swb)); \
      } \
  } while (0)

// 8 MFMAs: quarter q (rows q*32..+31) x column-half ch (cols ch*32..+31)
#define MFMA8(q, ch, Aq) do { \
    __builtin_amdgcn_s_setprio(1); \
_Pragma("unroll") \
    for (int mf2 = 0; mf2 < 2; ++mf2) \
_Pragma("unroll") \
      for (int nf = 0; nf < 2; ++nf) \
_Pragma("unroll") \
        for (int ks = 0; ks < 2; ++ks) \
          acc[(q) * 2 + mf2][(ch) * 2 + nf] = __builtin_amdgcn_mfma_f32_16x16x32_bf16( \
              Aq[mf2 * 2 + ks], Breg[(ch) * 4 + nf * 2 + ks], acc[(q) * 2 + mf2][(ch) * 2 + nf], 0, 0, 0); \
    __builtin_amdgcn_s_setprio(0); \
  } while (0)

#define WAIT_LGKM(n) do { \
    asm volatile("s_waitcnt lgkmcnt(" #n ")" ::: "memory"); \
    __builtin_amdgcn_sched_barrier(0); \
  } while (0)

  short8 Aq0[4], Aq1[4], Breg[8];

  // prologue: stage tile 0, drain, join
  STAGE(0);
  asm volatile("s_waitcnt vmcnt(0)" ::: "memory");
  asm volatile("s_barrier" ::: "memory");

  for (int t = 0; t < 16; ++t) {
    const unsigned sA = ldsBase + (unsigned)((t & 1) * 65536);
    const unsigned sB = sA + 32768u;

    // stage t+1 into the other slot (its previous readers finished before
    // the barrier we just passed)
    if (t < 15) STAGE(t + 1);

    // 16-deep burst: AQ0, B(ch0), B(ch1), AQ1
    READ_AQ(Aq0, 0);
    READ_B(0);
    READ_B(1);
    READ_AQ(Aq1, 1);

    WAIT_LGKM(8);                       // AQ0 + B(ch0) landed
    MFMA8(0, 0, Aq0);
    WAIT_LGKM(4);                       // + B(ch1) landed
    MFMA8(0, 1, Aq0);
    WAIT_LGKM(0);                       // + AQ1 landed
    READ_AQ(Aq0, 2);                    // prefetch q2 (reuse Aq0; WAR via reg dep)
    MFMA8(1, 0, Aq1);
    MFMA8(1, 1, Aq1);
    READ_AQ(Aq1, 3);                    // prefetch q3
    WAIT_LGKM(4);                       // AQ2 landed (AQ3 in flight)
    MFMA8(2, 0, Aq0);
    MFMA8(2, 1, Aq0);
    WAIT_LGKM(0);                       // AQ3 landed
    MFMA8(3, 0, Aq1);
    MFMA8(3, 1, Aq1);

    if (t < 15) {
      asm volatile("s_waitcnt vmcnt(0)" ::: "memory");  // only stage(t+1) outstanding
      asm volatile("s_barrier" ::: "memory");
    }
  }

  // epilogue: s[m] = sum_n tanh(acc + colb[n]) * Wa[n], reduce over l15
  float colb[4], wav[4];
#pragma unroll
  for (int nf = 0; nf < 4; ++nf) {
    int cg = n0 + wn * 64 + nf * 16 + l15;
    colb[nf] = att2pre[bb * 1024 + cg] + bfv[cg] + bdv[cg];
    wav[nf]  = Wa[cg];
  }
#pragma unroll
  for (int mf = 0; mf < 8; ++mf) {
#pragma unroll
    for (int r = 0; r < 4; ++r) {
      float s = tanh_fast(acc[mf][0][r] + colb[0]) * wav[0]
              + tanh_fast(acc[mf][1][r] + colb[1]) * wav[1]
              + tanh_fast(acc[mf][2][r] + colb[2]) * wav[2]
              + tanh_fast(acc[mf][3][r] + colb[3]) * wav[3];
      s += __shfl_xor(s, 1);
      s += __shfl_xor(s, 2);
      s += __shfl_xor(s, 4);
      s += __shfl_xor(s, 8);
      if (l15 == 0)
        atomicAdd(scores + (m0 + wm * 128 + mf * 16 + l4 * 4 + r), s);
    }
  }
#undef STAGE
#undef DSREAD
#undef READ_AQ
#undef READ_B
#undef MFMA8
#undef WAIT_LGKM
}

// ---------------------------------------------------------------------------
__global__ __launch_bounds__(256) void softmax_k(
    const float* __restrict__ scores, const int* __restrict__ mask,
    float* __restrict__ alpha)
{
  const int b = blockIdx.x, tid = threadIdx.x;
  __shared__ float red[8];
  float s[4];
  float mx = -3.0e38f;
#pragma unroll
  for (int i = 0; i < 4; ++i) {
    int l = tid + i * 256;
    float v = scores[b * 1024 + l];
    v = (mask[b * 1024 + l] == 0) ? -1.0e10f : v;
    s[i] = v;
    mx = fmaxf(mx, v);
  }
  for (int off = 1; off < 64; off <<= 1) mx = fmaxf(mx, __shfl_xor(mx, off));
  int wv = tid >> 6;
  if ((tid & 63) == 0) red[wv] = mx;
  __syncthreads();
  mx = fmaxf(fmaxf(red[0], red[1]), fmaxf(red[2], red[3]));
  float sum = 0.f;
#pragma unroll
  for (int i = 0; i < 4; ++i) {
    s[i] = exp2f_fast((s[i] - mx) * LOG2E);
    sum += s[i];
  }
  for (int off = 1; off < 64; off <<= 1) sum += __shfl_xor(sum, off);
  if ((tid & 63) == 0) red[4 + wv] = sum;
  __syncthreads();
  sum = red[4] + red[5] + red[6] + red[7];
  float inv = 1.0f / sum;
#pragma unroll
  for (int i = 0; i < 4; ++i) alpha[b * 1024 + tid + i * 256] = s[i] * inv;
}

// ---------------------------------------------------------------------------
__global__ __launch_bounds__(256) void ctx_kb(
    const unsigned short* __restrict__ capb, const float* __restrict__ alpha,
    float* __restrict__ ctx)
{
  const int b = blockIdx.y, lc = blockIdx.x;
  const int dc = threadIdx.x & 127, loff = threadIdx.x >> 7;
  float acc[8] = {0.f, 0.f, 0.f, 0.f, 0.f, 0.f, 0.f, 0.f};
  for (int l = lc * 128 + loff; l < lc * 128 + 128; l += 2) {
    float av = alpha[b * 1024 + l];
    if (av != 0.f) {
      short8 v = *reinterpret_cast<const short8*>(capb + (((size_t)(b * 1024 + l)) << 10) + dc * 8);
#pragma unroll
      for (int j = 0; j < 8; ++j) acc[j] += av * b2f(v[j]);
    }
  }
#pragma unroll
  for (int j = 0; j < 8; ++j) atomicAdd(ctx + b * 1024 + dc * 8 + j, acc[j]);
}

// ---------------------------------------------------------------------------
__global__ __launch_bounds__(256) void final_k(
    const float* __restrict__ ztp, const float* __restrict__ scp,
    const float* __restrict__ tcp, const float* __restrict__ bg,
    const float* __restrict__ bs, const float* __restrict__ bt,
    float* __restrict__ out)
{
  const int idx = blockIdx.x * 256 + threadIdx.x;
  const int d = idx & 1023;
  float z  = rcp_fast(1.0f + exp2f_fast(-(ztp[idx] + bg[d]) * LOG2E));
  float sc = tanh_fast(scp[idx] + bs[d]);
  float tc = tanh_fast(tcp[idx] + bt[d]);
  out[idx] = z * sc + (1.0f - z) * tc;
}

extern "C" void kernel_launch(void* const* d_in, const int* in_sizes, int n_in,
                              void* d_out, int out_size, void* d_ws, size_t ws_size,
                              hipStream_t stream) {
  const float* cap  = (const float*)d_in[0];
  const float* dh   = (const float*)d_in[1];
  const float* word = (const float*)d_in[2];
  const int*   mask = (const int*)d_in[3];
  const float* Wf   = (const float*)d_in[4];
  const float* bf   = (const float*)d_in[5];
  const float* Wd   = (const float*)d_in[6];
  const float* bd   = (const float*)d_in[7];
  const float* Wa   = (const float*)d_in[8];
  // d_in[9] = ba: softmax-invariant, dropped.
  const float* Wg   = (const float*)d_in[10];
  const float* bg   = (const float*)d_in[11];
  const float* Ws   = (const float*)d_in[12];
  const float* bs   = (const float*)d_in[13];
  const float* Wt   = (const float*)d_in[14];
  const float* bt   = (const float*)d_in[15];

  float* out_g = (float*)d_out;            // (32,1024) gated_context
  float* alpha = (float*)d_out + 32768;    // (32,1024) alpha

  float* att2pre = (float*)d_ws;           // 6 x 32768 f32
  float* scores  = att2pre + 32768;
  float* ctx     = scores + 32768;
  float* ztp     = ctx + 32768;
  float* scp     = ztp + 32768;
  float* tcp     = scp + 32768;
  unsigned short* capb = (unsigned short*)((char*)d_ws + 786432);
  unsigned short* wfb  = capb + 33554432;

  hipMemsetAsync(d_ws, 0, 6 * 32768 * sizeof(float), stream);

  convert_att2<<<2064, 256, 0, stream>>>(cap, Wf, capb, wfb, Wd, dh, att2pre, 2048);
  att_gemm3<<<512, 512, 0, stream>>>(capb, wfb, att2pre, bf, bd, Wa, scores);
  softmax_k<<<32, 256, 0, stream>>>(scores, mask, alpha);
  ctx_kb<<<dim3(8, 32), 256, 0, stream>>>(capb, alpha, ctx);
  gate_gemm<<<dim3(8, 12), 256, 0, stream>>>(Wg, Ws, Wt, word, dh, ctx, ztp, scp, tcp);
  final_k<<<128, 256, 0, stream>>>(ztp, scp, tcp, bg, bs, bt, out_g);
}